// Round 11
// baseline (148.257 us; speedup 1.0000x reference)
//
#include <hip/hip_runtime.h>
#include <math.h>

constexpr int Bb = 2;
constexpr int Nn = 2048;
constexpr int Cc = 512;
constexpr int Hh = 8;
constexpr int Dd = 64;

typedef short short8 __attribute__((ext_vector_type(8)));
typedef float floatx4 __attribute__((ext_vector_type(4)));
typedef float floatx16 __attribute__((ext_vector_type(16)));

__device__ inline short8 bcs8(uint4 u) { return __builtin_bit_cast(short8, u); }

__device__ inline floatx4 mfma16(short8 a, short8 b, floatx4 c) {
    return __builtin_amdgcn_mfma_f32_16x16x32_bf16(a, b, c, 0, 0, 0);
}
__device__ inline floatx16 mfma32(short8 a, short8 b, floatx16 c) {
    return __builtin_amdgcn_mfma_f32_32x32x16_bf16(a, b, c, 0, 0, 0);
}

#if __has_builtin(__builtin_amdgcn_exp2f)
#define EXP2(x) __builtin_amdgcn_exp2f(x)
#else
#define EXP2(x) __expf((x) * 0.69314718056f)
#endif

// pack bf16(a)|bf16(b)<<16, truncation (hi/lo splits: lo compensates hi)
__device__ inline unsigned pk_trunc(float a, float b) {
    return __builtin_amdgcn_perm(__float_as_uint(b), __float_as_uint(a), 0x07060302u);
}
// RNE pack
__device__ inline unsigned pk_rne(float a, float b) {
    unsigned ua = __float_as_uint(a); ua += 0x7fffu + ((ua >> 16) & 1u);
    unsigned ub = __float_as_uint(b); ub += 0x7fffu + ((ub >> 16) & 1u);
    return __builtin_amdgcn_perm(ub, ua, 0x07060302u);
}
__device__ inline unsigned short rne1(float a) {
    unsigned u = __float_as_uint(a); u += 0x7fffu + ((u >> 16) & 1u);
    return (unsigned short)(u >> 16);
}
__device__ inline float tr16(float a) {
    return __uint_as_float(__float_as_uint(a) & 0xffff0000u);
}
__device__ inline void split8(float4 A, float4 B, uint4& hi, uint4& lo) {
    hi = make_uint4(pk_trunc(A.x, A.y), pk_trunc(A.z, A.w),
                    pk_trunc(B.x, B.y), pk_trunc(B.z, B.w));
    lo = make_uint4(pk_trunc(A.x - tr16(A.x), A.y - tr16(A.y)),
                    pk_trunc(A.z - tr16(A.z), A.w - tr16(A.w)),
                    pk_trunc(B.x - tr16(B.x), B.y - tr16(B.y)),
                    pk_trunc(B.z - tr16(B.z), B.w - tr16(B.w)));
}

// Fragment-major layout (16x16x32 MFMA operand):
//   frag(idx, kc, comp): 1 KB at (((idx*16 + kc)*2 + comp) * 512) shorts;
//   lane l holds elem[row l&15][k kc*32 + (l>>4)*8 + jj], 8 bf16 = 16 B.

// ---------------------------------------------------------------------------
// prep (R6 fragment-centric): bid>=256 -> x -> xfrag (contiguous 1KB
// fragment writes — R8 lesson: gemm_qkv MUST read lane-major fragments).
// bid<256 -> weights transpose+split.
// ---------------------------------------------------------------------------
__global__ __launch_bounds__(256) void prep(const float* __restrict__ qkv_w,
                                            const float* __restrict__ proj_w,
                                            const float* __restrict__ x,
                                            unsigned short* __restrict__ wqfrag,
                                            unsigned short* __restrict__ wpfrag,
                                            unsigned short* __restrict__ xfrag)
{
    int bid = blockIdx.x;
    int t = threadIdx.x;
    if (bid >= 256) {                      // ---- x -> A-frag split ----
        int mt = bid - 256;                // token slab of 16
        const float* xs = x + (size_t)mt * 16 * 512;
        unsigned short* slab = xfrag + (size_t)mt * 16384;   // 16 fragpairs
        #pragma unroll
        for (int i = 0; i < 4; ++i) {
            int q = i * 256 + t;           // 0..1023 over (kc, f)
            int kc = q >> 6, f = q & 63;   // wave-uniform kc; f = lane
            int m = f & 15, o = f >> 4;    // frag row, k-octet
            const float* p = xs + m * 512 + kc * 32 + o * 8;
            float4 A = *(const float4*)p;
            float4 B = *(const float4*)(p + 4);
            uint4 hi, lo; split8(A, B, hi, lo);
            unsigned short* d = slab + kc * 1024 + f * 8;
            *(uint4*)d = hi;               // wave: contiguous 1KB
            *(uint4*)(d + 512) = lo;       // wave: contiguous 1KB
        }
        return;
    }
    // ---- weight transpose + split, direct column-gather ----
    const float* src; unsigned short* dfrag; int W, f0, k0;
    if (bid < 192) { int kt = bid / 24, ft = bid % 24; W = 1536; src = qkv_w; dfrag = wqfrag; f0 = ft * 64; k0 = kt * 64; }
    else { int b2 = bid - 192; int kt = b2 / 8, ft = b2 % 8; W = 512; src = proj_w; dfrag = wpfrag; f0 = ft * 64; k0 = kt * 64; }
    #pragma unroll
    for (int i = 0; i < 2; ++i) {
        int s = i * 256 + t;               // 0..511 over (fragpair, lane)
        int fp = s >> 6, l = s & 63;       // wave-uniform fragpair
        int nt = fp >> 1, kc = fp & 1;
        int m = l & 15, o = l >> 4;
        int f = f0 + nt * 16 + m;
        int kbase = k0 + kc * 32 + o * 8;
        float F[8];
        #pragma unroll
        for (int j = 0; j < 8; ++j) F[j] = src[(size_t)(kbase + j) * W + f];
        uint4 hi, lo;
        split8(make_float4(F[0], F[1], F[2], F[3]),
               make_float4(F[4], F[5], F[6], F[7]), hi, lo);
        int ntg = (f0 >> 4) + nt, kcg = (k0 >> 5) + kc;
        unsigned short* d = dfrag + ((size_t)(ntg * 16 + kcg) * 2) * 512 + l * 8;
        *(uint4*)d = hi;                   // wave: contiguous 1KB
        *(uint4*)(d + 512) = lo;           // wave: contiguous 1KB
    }
}

// ---------------------------------------------------------------------------
// GEMM1 with LDS-staged A (new this round). Same tile/grid/occupancy as the
// R6 best (64 tok x 128 col, 4 waves x 4mt x 2nt, grid (12,64), (256,3)).
// R8 counters showed MfmaUtil 12% / VALUBusy 18% with no spills and R10
// showed wave-count insensitivity -> the binding pipe is per-CU vector-
// memory issue: 48 x 1KB load-instrs per block-kc (A fragments loaded 4x
// redundantly by the 4 waves). Fix = canonical LDS staging (guide m93->m97,
// +69% on this exact symptom): stage the 8 shared A fragments (8 KB) into
// LDS once per kc (reg-staged, double-buffered), all waves ds_read_b128
// them. Vector-pipe traffic per block-kc: 48 KB -> 24 KB; A dedup 4x->1x;
// A-reads move to the separate LDS pipe (conflict-free: 64 lanes x 16B
// contiguous). Loads for kc+1 issue right after barrier1 so compute covers
// their latency (vmcnt drains at barrier2). Data copied verbatim ->
// bit-identical numerics. LDS 16 KB; VGPR ~90 < 170 cap.
// ---------------------------------------------------------------------------
__global__ __launch_bounds__(256, 3) void gemm_qkv(const unsigned short* __restrict__ xfrag,
                                                   const unsigned short* __restrict__ wqfrag,
                                                   unsigned short* __restrict__ qd,
                                                   unsigned short* __restrict__ kfrag,
                                                   unsigned short* __restrict__ vfrag)
{
    __shared__ unsigned short Abuf[2][4096];   // 2 bufs x 8 frags x 512 shorts
    const int tid = threadIdx.x, lane = tid & 63, w = tid >> 6;
    const int l15 = lane & 15, l4 = lane >> 4;
    const int row0 = blockIdx.y * 64, col0 = blockIdx.x * 128;
    const int mt0 = row0 >> 4;             // 4 consecutive mt
    const int nt0 = (col0 >> 4) + w * 2;   // 2 consecutive nt per wave

    floatx4 acc[4][2];
    #pragma unroll
    for (int i = 0; i < 4; ++i)
        #pragma unroll
        for (int j = 0; j < 2; ++j)
            #pragma unroll
            for (int r = 0; r < 4; ++r) acc[i][j][r] = 0.f;

    const unsigned short* wb = wqfrag + (size_t)lane * 8;

    // ---- staging helpers: thread t copies chunks c = t, t+256 of the
    // 8 KB A-slab for step kc. chunk c: frag f = c>>6 (mt = f>>1,
    // comp = f&1), intra-frag 16B index j = c&63. dst linear = c*16 B.
    // src: consecutive threads read consecutive 16B (waves frag-aligned).
    uint4 vst[2];
    {   // prologue: load + store kc=0 into buf 0
        #pragma unroll
        for (int i = 0; i < 2; ++i) {
            int c = i * 256 + tid;
            int f = c >> 6, j = c & 63;
            const unsigned short* s = xfrag +
                ((size_t)((mt0 + (f >> 1)) * 16 + 0) * 2 + (f & 1)) * 512 + j * 8;
            vst[i] = *(const uint4*)s;
        }
        #pragma unroll
        for (int i = 0; i < 2; ++i)
            *(uint4*)(Abuf[0] + (i * 256 + tid) * 8) = vst[i];
    }

    int cur = 0;
    for (int kc = 0; kc < 16; ++kc) {
        __syncthreads();                   // barrier1: Abuf[cur] ready
        uint4 vnx[2];
        if (kc < 15) {                     // issue next-step loads early;
            #pragma unroll                 // compute below covers latency
            for (int i = 0; i < 2; ++i) {
                int c = i * 256 + tid;
                int f = c >> 6, j = c & 63;
                const unsigned short* s = xfrag +
                    ((size_t)((mt0 + (f >> 1)) * 16 + (kc + 1)) * 2 + (f & 1)) * 512 + j * 8;
                vnx[i] = *(const uint4*)s;
            }
        }
        // ---- compute from Abuf[cur] ----
        short8 bf[2][2];
        #pragma unroll
        for (int nt = 0; nt < 2; ++nt) {
            size_t fb_ = ((size_t)((nt0 + nt) * 16 + kc) * 2) * 512;
            bf[nt][0] = bcs8(*(const uint4*)(wb + fb_));
            bf[nt][1] = bcs8(*(const uint4*)(wb + fb_ + 512));
        }
        const unsigned short* Ac = Abuf[cur];
        #pragma unroll
        for (int mt = 0; mt < 4; ++mt) {
            short8 ah = bcs8(*(const uint4*)(Ac + (mt * 2 + 0) * 512 + lane * 8));
            short8 al = bcs8(*(const uint4*)(Ac + (mt * 2 + 1) * 512 + lane * 8));
            #pragma unroll
            for (int nt = 0; nt < 2; ++nt) {
                acc[mt][nt] = mfma16(ah, bf[nt][0], acc[mt][nt]);
                acc[mt][nt] = mfma16(ah, bf[nt][1], acc[mt][nt]);
                acc[mt][nt] = mfma16(al, bf[nt][0], acc[mt][nt]);
            }
        }
        __syncthreads();                   // barrier2: all readers done
        if (kc < 15) {
            #pragma unroll
            for (int i = 0; i < 2; ++i)
                *(uint4*)(Abuf[cur ^ 1] + (i * 256 + tid) * 8) = vnx[i];
        }
        cur ^= 1;
    }

    // epilogue: q row-major (scaled); K scatter to kfrag; V dense to vfrag.
    #pragma unroll
    for (int mt = 0; mt < 4; ++mt)
        #pragma unroll
        for (int nt = 0; nt < 2; ++nt) {
            int c = col0 + (w * 2 + nt) * 16 + l15;      // 0..1535
            int which = c >> 9;                          // 0=q,1=k,2=v (wave-uniform)
            int head = (c >> 6) & 7, d = c & 63;
            int tokb = row0 + mt * 16 + l4 * 4;
            int b = tokb >> 11, nn = tokb & 2047;
            int bh = b * 8 + head;
            if (which == 0) {
                #pragma unroll
                for (int r = 0; r < 4; ++r)
                    qd[(size_t)(bh * 2048 + nn + r) * 64 + d] = rne1(acc[mt][nt][r] * 0.18033688f);
            } else if (which == 1) {
                int s = d >> 4;
                size_t fb_ = ((size_t)(bh * 64 + (nn >> 5)) * 4 + s) * 512 + (d & 7);
                int hl = ((d >> 3) & 1) * 32;
                #pragma unroll
                for (int r = 0; r < 4; ++r)
                    kfrag[fb_ + (size_t)(hl + ((nn + r) & 31)) * 8] = rne1(acc[mt][nt][r]);
            } else {
                int j = nn >> 4, mtv = d >> 5;
                uint2 pv;
                pv.x = pk_rne(acc[mt][nt][0], acc[mt][nt][1]);
                pv.y = pk_rne(acc[mt][nt][2], acc[mt][nt][3]);
                *(uint2*)&vfrag[((size_t)(bh * 128 + j) * 2 + mtv) * 512 +
                                (size_t)(((nn >> 3) & 1) * 32 + (d & 31)) * 8 + (nn & 7)] = pv;
            }
        }
}

// ---------------------------------------------------------------------------
// Attention (R6 config — best measured): 64 q per block, 4 kg-waves on
// 512-key strips, no in-loop LDS/barriers, XCD-grouped by bh. 2-stage
// parallel merge fold. No cross-block sync (R5). Epilogue honors the
// reference's buggy reshape: gemm2 row r = bh*256 + n/8, c = (n%8)*64+d.
// ---------------------------------------------------------------------------
__global__ __launch_bounds__(256, 2) void attn(const unsigned short* __restrict__ qd,
                                               const unsigned short* __restrict__ kfrag,
                                               const unsigned short* __restrict__ vfrag,
                                               unsigned short* __restrict__ Ofrag)
{
    __shared__ float Pp[2][64][65];    // two partial regions [q][d], pitch 65
    __shared__ float Lsp[2][64];       // two partial l regions [q]

    int bid = blockIdx.x;
    int xcd = bid & 7; int rr = bid >> 3;
    int qt = rr & 31; int bhi = rr >> 5;
    int bh = (bhi << 3) | xcd;
    int tid = threadIdx.x, lane = tid & 63, kg = tid >> 6;
    int l31 = lane & 31, h = lane >> 5;

    // Q^T fragments (B-operand), 2 query-halves of 32 (pre-scaled, log2e folded)
    short8 qf[2][4];
    #pragma unroll
    for (int qh = 0; qh < 2; ++qh)
        #pragma unroll
        for (int s = 0; s < 4; ++s)
            qf[qh][s] = bcs8(*(const uint4*)(qd + ((size_t)bh * 2048 + qt * 64 + qh * 32 + l31) * 64 + s * 16 + h * 8));

    const uint4 onesu = make_uint4(0x3F803F80u, 0x3F803F80u, 0x3F803F80u, 0x3F803F80u);
    const short8 onesf = bcs8(onesu);

    floatx16 OT[2][2], OTl[2];
    #pragma unroll
    for (int qh = 0; qh < 2; ++qh) {
        #pragma unroll
        for (int i = 0; i < 2; ++i)
            #pragma unroll
            for (int r = 0; r < 16; ++r) OT[qh][i][r] = 0.f;
        #pragma unroll
        for (int r = 0; r < 16; ++r) OTl[qh][r] = 0.f;
    }

    const unsigned short* kb_ = kfrag + ((size_t)(bh * 64 + kg * 16) * 4) * 512 + lane * 8;
    const unsigned short* vb_ = vfrag + ((size_t)(bh * 128 + kg * 32) * 2) * 512 + lane * 8;

    #pragma unroll
    for (int c = 0; c < 16; ++c) {
        uint4 kfu[4];
        #pragma unroll
        for (int s = 0; s < 4; ++s)
            kfu[s] = *(const uint4*)(kb_ + ((size_t)c * 4 + s) * 512);
        uint4 vfu[2][2];
        #pragma unroll
        for (int kc = 0; kc < 2; ++kc)
            #pragma unroll
            for (int mtv = 0; mtv < 2; ++mtv)
                vfu[kc][mtv] = *(const uint4*)(vb_ + ((size_t)(c * 2 + kc) * 2 + mtv) * 512);

        #pragma unroll
        for (int qh = 0; qh < 2; ++qh) {
            floatx16 st;
            #pragma unroll
            for (int r = 0; r < 16; ++r) st[r] = 0.f;
            #pragma unroll
            for (int s = 0; s < 4; ++s) st = mfma32(bcs8(kfu[s]), qf[qh][s], st);

            unsigned P2[8];
            #pragma unroll
            for (int s2 = 0; s2 < 8; ++s2)
                P2[s2] = pk_trunc(EXP2(st[2 * s2]), EXP2(st[2 * s2 + 1]));

            #pragma unroll
            for (int kc = 0; kc < 2; ++kc) {
                unsigned X0 = P2[4 * kc + 0], X1 = P2[4 * kc + 1];
                unsigned Y0 = P2[4 * kc + 2], Y1 = P2[4 * kc + 3];
                unsigned T0 = h ? X0 : Y0;
                unsigned T1 = h ? X1 : Y1;
                unsigned To0 = __shfl_xor(T0, 32, 64);
                unsigned To1 = __shfl_xor(T1, 32, 64);
                uint4 fu;
                fu.x = h ? To0 : X0;
                fu.y = h ? To1 : X1;
                fu.z = h ? Y0 : To0;
                fu.w = h ? Y1 : To1;
                short8 pf = bcs8(fu);
                OT[qh][0] = mfma32(bcs8(vfu[kc][0]), pf, OT[qh][0]);
                OT[qh][1] = mfma32(bcs8(vfu[kc][1]), pf, OT[qh][1]);
                OTl[qh] = mfma32(onesf, pf, OTl[qh]);   // l += column-sums of rounded P
            }
        }
    }

    // ---- merge: 2-stage parallel fold across the 4 kg waves ----
    if (kg < 2) {
        #pragma unroll
        for (int qh = 0; qh < 2; ++qh) {
            int q = qh * 32 + l31;
            #pragma unroll
            for (int mtv = 0; mtv < 2; ++mtv)
                #pragma unroll
                for (int r = 0; r < 16; ++r) {
                    int d = mtv * 32 + (r & 3) + 8 * (r >> 2) + 4 * h;
                    Pp[kg][q][d] = OT[qh][mtv][r];
                }
            Lsp[kg][q] = OTl[qh][0];        // both h halves write same value
        }
    }
    __syncthreads();
    if (kg >= 2) {
        #pragma unroll
        for (int qh = 0; qh < 2; ++qh) {
            int q = qh * 32 + l31;
            #pragma unroll
            for (int mtv = 0; mtv < 2; ++mtv)
                #pragma unroll
                for (int r = 0; r < 16; ++r) {
                    int d = mtv * 32 + (r & 3) + 8 * (r >> 2) + 4 * h;
                    Pp[kg - 2][q][d] += OT[qh][mtv][r];
                }
            if (h == 0) Lsp[kg - 2][q] += OTl[qh][0];   // RMW: single h half only
        }
    }
    __syncthreads();
    // all 256 threads: final 2-way sum, 1/l scale, split-bf16 store to Ofrag.
    {
        int q = tid >> 2, dc = (tid & 3) * 16;              // q 0..63, dc 0/16/32/48
        float linv = 1.f / (Lsp[0][q] + Lsp[1][q]);
        float vv[16];
        #pragma unroll
        for (int i = 0; i < 16; ++i)
            vv[i] = (Pp[0][q][dc + i] + Pp[1][q][dc + i]) * linv;
        unsigned hi[8], lo[8];
        #pragma unroll
        for (int i = 0; i < 8; ++i) {
            float a = vv[2 * i], bb = vv[2 * i + 1];
            hi[i] = pk_trunc(a, bb);
            lo[i] = pk_trunc(a - tr16(a), bb - tr16(bb));
        }
        int ng = qt * 64 + q;                               // token within bh
        int r = bh * 256 + (ng >> 3);                       // gemm2 row
        int mt = r >> 4, m = r & 15;
        #pragma unroll
        for (int hh = 0; hh < 2; ++hh) {
            int cc = (ng & 7) * 64 + dc + hh * 8;           // gemm2 col (octet-aligned)
            int kc = cc >> 5, oct = (cc >> 3) & 3;
            unsigned short* fb_ = Ofrag + ((size_t)(mt * 16 + kc) * 2) * 512 + (m + 16 * oct) * 8;
            *(uint4*)fb_ = make_uint4(hi[4 * hh + 0], hi[4 * hh + 1], hi[4 * hh + 2], hi[4 * hh + 3]);
            *(uint4*)(fb_ + 512) = make_uint4(lo[4 * hh + 0], lo[4 * hh + 1], lo[4 * hh + 2], lo[4 * hh + 3]);
        }
    }
}

// ---------------------------------------------------------------------------
// GEMM2 (R6 config — best measured): barrier-free, zero-LDS. Block =
// 64 rows x 64 cols; 4 waves (2x2), each 2 mt x 2 nt. grid (8, 64) = 512
// blocks, 2/CU. out = Ofrag @ wpfrag + bias.
// ---------------------------------------------------------------------------
__global__ __launch_bounds__(256, 2) void gemm_proj(const unsigned short* __restrict__ Ofrag,
                                                    const unsigned short* __restrict__ wpfrag,
                                                    const float* __restrict__ bias,
                                                    float* __restrict__ out)
{
    const int tid = threadIdx.x, lane = tid & 63, w = tid >> 6;
    const int l15 = lane & 15, l4 = lane >> 4;
    const int row0 = blockIdx.y * 64, col0 = blockIdx.x * 64;
    const int wm = w >> 1, wn = w & 1;
    const int mt0 = (row0 >> 4) + wm * 2;
    const int nt0 = (col0 >> 4) + wn * 2;

    floatx4 acc[2][2];
    #pragma unroll
    for (int i = 0; i < 2; ++i)
        #pragma unroll
        for (int j = 0; j < 2; ++j)
            #pragma unroll
            for (int r = 0; r < 4; ++r) acc[i][j][r] = 0.f;

    const unsigned short* ab = Ofrag + (size_t)lane * 8;
    const unsigned short* wb = wpfrag + (size_t)lane * 8;

    #pragma unroll
    for (int kc = 0; kc < 16; ++kc) {
        short8 bf[2][2];
        #pragma unroll
        for (int nt = 0; nt < 2; ++nt) {
            size_t fb_ = ((size_t)((nt0 + nt) * 16 + kc) * 2) * 512;
            bf[nt][0] = bcs8(*(const uint4*)(wb + fb_));
            bf[nt][1] = bcs8(*(const uint4*)(wb + fb_ + 512));
        }
        #pragma unroll
        for (int mt = 0; mt < 2; ++mt) {
            size_t fa_ = ((size_t)((mt0 + mt) * 16 + kc) * 2) * 512;
            short8 ah = bcs8(*(const uint4*)(ab + fa_));
            short8 al = bcs8(*(const uint4*)(ab + fa_ + 512));
            #pragma unroll
            for (int nt = 0; nt < 2; ++nt) {
                acc[mt][nt] = mfma16(ah, bf[nt][0], acc[mt][nt]);
                acc[mt][nt] = mfma16(ah, bf[nt][1], acc[mt][nt]);
                acc[mt][nt] = mfma16(al, bf[nt][0], acc[mt][nt]);
            }
        }
    }
    #pragma unroll
    for (int mt = 0; mt < 2; ++mt)
        #pragma unroll
        for (int nt = 0; nt < 2; ++nt) {
            int c = col0 + wn * 32 + nt * 16 + l15;
            float bv = bias[c];
            #pragma unroll
            for (int r = 0; r < 4; ++r) {
                int tok = row0 + wm * 32 + mt * 16 + l4 * 4 + r;
                out[(size_t)tok * 512 + c] = acc[mt][nt][r] + bv;
            }
        }
}

// ---------------------------------------------------------------------------
extern "C" void kernel_launch(void* const* d_in, const int* in_sizes, int n_in,
                              void* d_out, int out_size, void* d_ws, size_t ws_size,
                              hipStream_t stream)
{
    const float* x      = (const float*)d_in[0];
    const float* qkv_w  = (const float*)d_in[1];
    const float* proj_w = (const float*)d_in[2];
    const float* proj_b = (const float*)d_in[3];
    float* out = (float*)d_out;

    char* ws = (char*)d_ws;
    unsigned short* xfrag  = (unsigned short*)ws;                     //  8 MiB
    unsigned short* wqfrag = (unsigned short*)(ws + 8388608);         //  3 MiB
    unsigned short* wpfrag = (unsigned short*)(ws + 11534336);        //  1 MiB
    unsigned short* qd     = (unsigned short*)(ws + 12582912);        //  4 MiB
    unsigned short* kfrag  = (unsigned short*)(ws + 16777216);        //  4 MiB
    unsigned short* vfrag  = (unsigned short*)(ws + 20971520);        //  4 MiB
    unsigned short* Ofrag  = (unsigned short*)(ws + 25165824);        //  8 MiB (end 32 MiB)

    prep<<<512, 256, 0, stream>>>(qkv_w, proj_w, x, wqfrag, wpfrag, xfrag);
    gemm_qkv<<<dim3(12, 64), 256, 0, stream>>>(xfrag, wqfrag, qd, kfrag, vfrag);
    attn<<<512, 256, 0, stream>>>(qd, kfrag, vfrag, Ofrag);
    gemm_proj<<<dim3(8, 64), 256, 0, stream>>>(Ofrag, wpfrag, proj_b, out);
}

// Round 12
// 136.122 us; speedup vs baseline: 1.0891x; 1.0891x over previous
//
#include <hip/hip_runtime.h>
#include <math.h>

constexpr int Bb = 2;
constexpr int Nn = 2048;
constexpr int Cc = 512;
constexpr int Hh = 8;
constexpr int Dd = 64;

typedef short short8 __attribute__((ext_vector_type(8)));
typedef float floatx4 __attribute__((ext_vector_type(4)));
typedef float floatx16 __attribute__((ext_vector_type(16)));

__device__ inline short8 bcs8(uint4 u) { return __builtin_bit_cast(short8, u); }

__device__ inline floatx4 mfma16(short8 a, short8 b, floatx4 c) {
    return __builtin_amdgcn_mfma_f32_16x16x32_bf16(a, b, c, 0, 0, 0);
}
__device__ inline floatx16 mfma32(short8 a, short8 b, floatx16 c) {
    return __builtin_amdgcn_mfma_f32_32x32x16_bf16(a, b, c, 0, 0, 0);
}

#if __has_builtin(__builtin_amdgcn_exp2f)
#define EXP2(x) __builtin_amdgcn_exp2f(x)
#else
#define EXP2(x) __expf((x) * 0.69314718056f)
#endif

// pack bf16(a)|bf16(b)<<16, truncation (hi/lo splits: lo compensates hi)
__device__ inline unsigned pk_trunc(float a, float b) {
    return __builtin_amdgcn_perm(__float_as_uint(b), __float_as_uint(a), 0x07060302u);
}
// RNE pack
__device__ inline unsigned pk_rne(float a, float b) {
    unsigned ua = __float_as_uint(a); ua += 0x7fffu + ((ua >> 16) & 1u);
    unsigned ub = __float_as_uint(b); ub += 0x7fffu + ((ub >> 16) & 1u);
    return __builtin_amdgcn_perm(ub, ua, 0x07060302u);
}
__device__ inline unsigned short rne1(float a) {
    unsigned u = __float_as_uint(a); u += 0x7fffu + ((u >> 16) & 1u);
    return (unsigned short)(u >> 16);
}
__device__ inline float tr16(float a) {
    return __uint_as_float(__float_as_uint(a) & 0xffff0000u);
}
__device__ inline void split8(float4 A, float4 B, uint4& hi, uint4& lo) {
    hi = make_uint4(pk_trunc(A.x, A.y), pk_trunc(A.z, A.w),
                    pk_trunc(B.x, B.y), pk_trunc(B.z, B.w));
    lo = make_uint4(pk_trunc(A.x - tr16(A.x), A.y - tr16(A.y)),
                    pk_trunc(A.z - tr16(A.z), A.w - tr16(A.w)),
                    pk_trunc(B.x - tr16(B.x), B.y - tr16(B.y)),
                    pk_trunc(B.z - tr16(B.z), B.w - tr16(B.w)));
}

// Fragment-major layout (16x16x32 MFMA operand):
//   frag(idx, kc, comp): 1 KB at (((idx*16 + kc)*2 + comp) * 512) shorts;
//   lane l holds elem[row l&15][k kc*32 + (l>>4)*8 + jj], 8 bf16 = 16 B.

// ---------------------------------------------------------------------------
// prep (R6 fragment-centric — best measured): bid>=256 -> x -> xfrag
// (contiguous 1KB fragment writes; R8 lesson: gemm_qkv MUST read lane-major
// fragments). bid<256 -> weights transpose+split.
// ---------------------------------------------------------------------------
__global__ __launch_bounds__(256) void prep(const float* __restrict__ qkv_w,
                                            const float* __restrict__ proj_w,
                                            const float* __restrict__ x,
                                            unsigned short* __restrict__ wqfrag,
                                            unsigned short* __restrict__ wpfrag,
                                            unsigned short* __restrict__ xfrag)
{
    int bid = blockIdx.x;
    int t = threadIdx.x;
    if (bid >= 256) {                      // ---- x -> A-frag split ----
        int mt = bid - 256;                // token slab of 16
        const float* xs = x + (size_t)mt * 16 * 512;
        unsigned short* slab = xfrag + (size_t)mt * 16384;   // 16 fragpairs
        #pragma unroll
        for (int i = 0; i < 4; ++i) {
            int q = i * 256 + t;           // 0..1023 over (kc, f)
            int kc = q >> 6, f = q & 63;   // wave-uniform kc; f = lane
            int m = f & 15, o = f >> 4;    // frag row, k-octet
            const float* p = xs + m * 512 + kc * 32 + o * 8;
            float4 A = *(const float4*)p;
            float4 B = *(const float4*)(p + 4);
            uint4 hi, lo; split8(A, B, hi, lo);
            unsigned short* d = slab + kc * 1024 + f * 8;
            *(uint4*)d = hi;               // wave: contiguous 1KB
            *(uint4*)(d + 512) = lo;       // wave: contiguous 1KB
        }
        return;
    }
    // ---- weight transpose + split, direct column-gather ----
    const float* src; unsigned short* dfrag; int W, f0, k0;
    if (bid < 192) { int kt = bid / 24, ft = bid % 24; W = 1536; src = qkv_w; dfrag = wqfrag; f0 = ft * 64; k0 = kt * 64; }
    else { int b2 = bid - 192; int kt = b2 / 8, ft = b2 % 8; W = 512; src = proj_w; dfrag = wpfrag; f0 = ft * 64; k0 = kt * 64; }
    #pragma unroll
    for (int i = 0; i < 2; ++i) {
        int s = i * 256 + t;               // 0..511 over (fragpair, lane)
        int fp = s >> 6, l = s & 63;       // wave-uniform fragpair
        int nt = fp >> 1, kc = fp & 1;
        int m = l & 15, o = l >> 4;
        int f = f0 + nt * 16 + m;
        int kbase = k0 + kc * 32 + o * 8;
        float F[8];
        #pragma unroll
        for (int j = 0; j < 8; ++j) F[j] = src[(size_t)(kbase + j) * W + f];
        uint4 hi, lo;
        split8(make_float4(F[0], F[1], F[2], F[3]),
               make_float4(F[4], F[5], F[6], F[7]), hi, lo);
        int ntg = (f0 >> 4) + nt, kcg = (k0 >> 5) + kc;
        unsigned short* d = dfrag + ((size_t)(ntg * 16 + kcg) * 2) * 512 + l * 8;
        *(uint4*)d = hi;                   // wave: contiguous 1KB
        *(uint4*)(d + 512) = lo;           // wave: contiguous 1KB
    }
}

// ---------------------------------------------------------------------------
// GEMM1 (R6 config — best measured): barrier-free, zero-LDS streaming.
// Block = 64 tok x 128 cols; 4 waves, each 4 mt x 2 nt, frag-major loads.
// grid (12,64) = 768 blocks, 3/CU. Session lessons pinned here:
//  - R3: do not trade blocks for bytes (occupancy cliff > L2-BW gain)
//  - R8: A must be read via lane-major fragments (direct strided x = +19us)
//  - R10: insensitive to more waves/CU (16 vs 12: neutral)
//  - R11: LDS-staging A regresses (+12us): 2 barriers/kc-step drain cost
//    exceeds the L1-served redundant-load cost at 3 blocks/CU.
// ---------------------------------------------------------------------------
__global__ __launch_bounds__(256, 3) void gemm_qkv(const unsigned short* __restrict__ xfrag,
                                                   const unsigned short* __restrict__ wqfrag,
                                                   unsigned short* __restrict__ qd,
                                                   unsigned short* __restrict__ kfrag,
                                                   unsigned short* __restrict__ vfrag)
{
    const int tid = threadIdx.x, lane = tid & 63, w = tid >> 6;
    const int l15 = lane & 15, l4 = lane >> 4;
    const int row0 = blockIdx.y * 64, col0 = blockIdx.x * 128;
    const int mt0 = row0 >> 4;             // 4 consecutive mt
    const int nt0 = (col0 >> 4) + w * 2;   // 2 consecutive nt per wave

    floatx4 acc[4][2];
    #pragma unroll
    for (int i = 0; i < 4; ++i)
        #pragma unroll
        for (int j = 0; j < 2; ++j)
            #pragma unroll
            for (int r = 0; r < 4; ++r) acc[i][j][r] = 0.f;

    const unsigned short* xb = xfrag + (size_t)lane * 8;
    const unsigned short* wb = wqfrag + (size_t)lane * 8;

    #pragma unroll
    for (int kc = 0; kc < 16; ++kc) {
        short8 bf[2][2];
        #pragma unroll
        for (int nt = 0; nt < 2; ++nt) {
            size_t fb_ = ((size_t)((nt0 + nt) * 16 + kc) * 2) * 512;
            bf[nt][0] = bcs8(*(const uint4*)(wb + fb_));
            bf[nt][1] = bcs8(*(const uint4*)(wb + fb_ + 512));
        }
        #pragma unroll
        for (int mt = 0; mt < 4; ++mt) {
            size_t fa_ = ((size_t)((mt0 + mt) * 16 + kc) * 2) * 512;
            short8 ah = bcs8(*(const uint4*)(xb + fa_));
            short8 al = bcs8(*(const uint4*)(xb + fa_ + 512));
            #pragma unroll
            for (int nt = 0; nt < 2; ++nt) {
                acc[mt][nt] = mfma16(ah, bf[nt][0], acc[mt][nt]);
                acc[mt][nt] = mfma16(ah, bf[nt][1], acc[mt][nt]);
                acc[mt][nt] = mfma16(al, bf[nt][0], acc[mt][nt]);
            }
        }
    }
    // epilogue: q row-major (scaled); K scatter to kfrag; V dense to vfrag.
    #pragma unroll
    for (int mt = 0; mt < 4; ++mt)
        #pragma unroll
        for (int nt = 0; nt < 2; ++nt) {
            int c = col0 + (w * 2 + nt) * 16 + l15;      // 0..1535
            int which = c >> 9;                          // 0=q,1=k,2=v (wave-uniform)
            int head = (c >> 6) & 7, d = c & 63;
            int tokb = row0 + mt * 16 + l4 * 4;
            int b = tokb >> 11, nn = tokb & 2047;
            int bh = b * 8 + head;
            if (which == 0) {
                #pragma unroll
                for (int r = 0; r < 4; ++r)
                    qd[(size_t)(bh * 2048 + nn + r) * 64 + d] = rne1(acc[mt][nt][r] * 0.18033688f);
            } else if (which == 1) {
                int s = d >> 4;
                size_t fb_ = ((size_t)(bh * 64 + (nn >> 5)) * 4 + s) * 512 + (d & 7);
                int hl = ((d >> 3) & 1) * 32;
                #pragma unroll
                for (int r = 0; r < 4; ++r)
                    kfrag[fb_ + (size_t)(hl + ((nn + r) & 31)) * 8] = rne1(acc[mt][nt][r]);
            } else {
                int j = nn >> 4, mtv = d >> 5;
                uint2 pv;
                pv.x = pk_rne(acc[mt][nt][0], acc[mt][nt][1]);
                pv.y = pk_rne(acc[mt][nt][2], acc[mt][nt][3]);
                *(uint2*)&vfrag[((size_t)(bh * 128 + j) * 2 + mtv) * 512 +
                                (size_t)(((nn >> 3) & 1) * 32 + (d & 31)) * 8 + (nn & 7)] = pv;
            }
        }
}

// ---------------------------------------------------------------------------
// Attention (R6 config — best measured): 64 q per block, 4 kg-waves on
// 512-key strips, no in-loop LDS/barriers, XCD-grouped by bh. 2-stage
// parallel merge fold. R5 lesson: no cross-block sync (agent-scope
// acquire/release storms the non-coherent per-XCD L2s). R9 lesson:
// insensitive to 8-wave K-split. Epilogue honors the reference's buggy
// reshape: gemm2 row r = bh*256 + n/8, col c = (n%8)*64+d.
// ---------------------------------------------------------------------------
__global__ __launch_bounds__(256, 2) void attn(const unsigned short* __restrict__ qd,
                                               const unsigned short* __restrict__ kfrag,
                                               const unsigned short* __restrict__ vfrag,
                                               unsigned short* __restrict__ Ofrag)
{
    __shared__ float Pp[2][64][65];    // two partial regions [q][d], pitch 65
    __shared__ float Lsp[2][64];       // two partial l regions [q]

    int bid = blockIdx.x;
    int xcd = bid & 7; int rr = bid >> 3;
    int qt = rr & 31; int bhi = rr >> 5;
    int bh = (bhi << 3) | xcd;
    int tid = threadIdx.x, lane = tid & 63, kg = tid >> 6;
    int l31 = lane & 31, h = lane >> 5;

    // Q^T fragments (B-operand), 2 query-halves of 32 (pre-scaled, log2e folded)
    short8 qf[2][4];
    #pragma unroll
    for (int qh = 0; qh < 2; ++qh)
        #pragma unroll
        for (int s = 0; s < 4; ++s)
            qf[qh][s] = bcs8(*(const uint4*)(qd + ((size_t)bh * 2048 + qt * 64 + qh * 32 + l31) * 64 + s * 16 + h * 8));

    const uint4 onesu = make_uint4(0x3F803F80u, 0x3F803F80u, 0x3F803F80u, 0x3F803F80u);
    const short8 onesf = bcs8(onesu);

    floatx16 OT[2][2], OTl[2];
    #pragma unroll
    for (int qh = 0; qh < 2; ++qh) {
        #pragma unroll
        for (int i = 0; i < 2; ++i)
            #pragma unroll
            for (int r = 0; r < 16; ++r) OT[qh][i][r] = 0.f;
        #pragma unroll
        for (int r = 0; r < 16; ++r) OTl[qh][r] = 0.f;
    }

    const unsigned short* kb_ = kfrag + ((size_t)(bh * 64 + kg * 16) * 4) * 512 + lane * 8;
    const unsigned short* vb_ = vfrag + ((size_t)(bh * 128 + kg * 32) * 2) * 512 + lane * 8;

    #pragma unroll
    for (int c = 0; c < 16; ++c) {
        uint4 kfu[4];
        #pragma unroll
        for (int s = 0; s < 4; ++s)
            kfu[s] = *(const uint4*)(kb_ + ((size_t)c * 4 + s) * 512);
        uint4 vfu[2][2];
        #pragma unroll
        for (int kc = 0; kc < 2; ++kc)
            #pragma unroll
            for (int mtv = 0; mtv < 2; ++mtv)
                vfu[kc][mtv] = *(const uint4*)(vb_ + ((size_t)(c * 2 + kc) * 2 + mtv) * 512);

        #pragma unroll
        for (int qh = 0; qh < 2; ++qh) {
            floatx16 st;
            #pragma unroll
            for (int r = 0; r < 16; ++r) st[r] = 0.f;
            #pragma unroll
            for (int s = 0; s < 4; ++s) st = mfma32(bcs8(kfu[s]), qf[qh][s], st);

            unsigned P2[8];
            #pragma unroll
            for (int s2 = 0; s2 < 8; ++s2)
                P2[s2] = pk_trunc(EXP2(st[2 * s2]), EXP2(st[2 * s2 + 1]));

            #pragma unroll
            for (int kc = 0; kc < 2; ++kc) {
                unsigned X0 = P2[4 * kc + 0], X1 = P2[4 * kc + 1];
                unsigned Y0 = P2[4 * kc + 2], Y1 = P2[4 * kc + 3];
                unsigned T0 = h ? X0 : Y0;
                unsigned T1 = h ? X1 : Y1;
                unsigned To0 = __shfl_xor(T0, 32, 64);
                unsigned To1 = __shfl_xor(T1, 32, 64);
                uint4 fu;
                fu.x = h ? To0 : X0;
                fu.y = h ? To1 : X1;
                fu.z = h ? Y0 : To0;
                fu.w = h ? Y1 : To1;
                short8 pf = bcs8(fu);
                OT[qh][0] = mfma32(bcs8(vfu[kc][0]), pf, OT[qh][0]);
                OT[qh][1] = mfma32(bcs8(vfu[kc][1]), pf, OT[qh][1]);
                OTl[qh] = mfma32(onesf, pf, OTl[qh]);   // l += column-sums of rounded P
            }
        }
    }

    // ---- merge: 2-stage parallel fold across the 4 kg waves ----
    if (kg < 2) {
        #pragma unroll
        for (int qh = 0; qh < 2; ++qh) {
            int q = qh * 32 + l31;
            #pragma unroll
            for (int mtv = 0; mtv < 2; ++mtv)
                #pragma unroll
                for (int r = 0; r < 16; ++r) {
                    int d = mtv * 32 + (r & 3) + 8 * (r >> 2) + 4 * h;
                    Pp[kg][q][d] = OT[qh][mtv][r];
                }
            Lsp[kg][q] = OTl[qh][0];        // both h halves write same value
        }
    }
    __syncthreads();
    if (kg >= 2) {
        #pragma unroll
        for (int qh = 0; qh < 2; ++qh) {
            int q = qh * 32 + l31;
            #pragma unroll
            for (int mtv = 0; mtv < 2; ++mtv)
                #pragma unroll
                for (int r = 0; r < 16; ++r) {
                    int d = mtv * 32 + (r & 3) + 8 * (r >> 2) + 4 * h;
                    Pp[kg - 2][q][d] += OT[qh][mtv][r];
                }
            if (h == 0) Lsp[kg - 2][q] += OTl[qh][0];   // RMW: single h half only
        }
    }
    __syncthreads();
    // all 256 threads: final 2-way sum, 1/l scale, split-bf16 store to Ofrag.
    {
        int q = tid >> 2, dc = (tid & 3) * 16;              // q 0..63, dc 0/16/32/48
        float linv = 1.f / (Lsp[0][q] + Lsp[1][q]);
        float vv[16];
        #pragma unroll
        for (int i = 0; i < 16; ++i)
            vv[i] = (Pp[0][q][dc + i] + Pp[1][q][dc + i]) * linv;
        unsigned hi[8], lo[8];
        #pragma unroll
        for (int i = 0; i < 8; ++i) {
            float a = vv[2 * i], bb = vv[2 * i + 1];
            hi[i] = pk_trunc(a, bb);
            lo[i] = pk_trunc(a - tr16(a), bb - tr16(bb));
        }
        int ng = qt * 64 + q;                               // token within bh
        int r = bh * 256 + (ng >> 3);                       // gemm2 row
        int mt = r >> 4, m = r & 15;
        #pragma unroll
        for (int hh = 0; hh < 2; ++hh) {
            int cc = (ng & 7) * 64 + dc + hh * 8;           // gemm2 col (octet-aligned)
            int kc = cc >> 5, oct = (cc >> 3) & 3;
            unsigned short* fb_ = Ofrag + ((size_t)(mt * 16 + kc) * 2) * 512 + (m + 16 * oct) * 8;
            *(uint4*)fb_ = make_uint4(hi[4 * hh + 0], hi[4 * hh + 1], hi[4 * hh + 2], hi[4 * hh + 3]);
            *(uint4*)(fb_ + 512) = make_uint4(lo[4 * hh + 0], lo[4 * hh + 1], lo[4 * hh + 2], lo[4 * hh + 3]);
        }
    }
}

// ---------------------------------------------------------------------------
// GEMM2 (R6 config — best measured): barrier-free, zero-LDS. Block =
// 64 rows x 64 cols; 4 waves (2x2), each 2 mt x 2 nt. grid (8, 64) = 512
// blocks, 2/CU. R9 lesson: insensitive to 8-wave K-split.
// out = Ofrag @ wpfrag + bias.
// ---------------------------------------------------------------------------
__global__ __launch_bounds__(256, 2) void gemm_proj(const unsigned short* __restrict__ Ofrag,
                                                    const unsigned short* __restrict__ wpfrag,
                                                    const float* __restrict__ bias,
                                                    float* __restrict__ out)
{
    const int tid = threadIdx.x, lane = tid & 63, w = tid >> 6;
    const int l15 = lane & 15, l4 = lane >> 4;
    const int row0 = blockIdx.y * 64, col0 = blockIdx.x * 64;
    const int wm = w >> 1, wn = w & 1;
    const int mt0 = (row0 >> 4) + wm * 2;
    const int nt0 = (col0 >> 4) + wn * 2;

    floatx4 acc[2][2];
    #pragma unroll
    for (int i = 0; i < 2; ++i)
        #pragma unroll
        for (int j = 0; j < 2; ++j)
            #pragma unroll
            for (int r = 0; r < 4; ++r) acc[i][j][r] = 0.f;

    const unsigned short* ab = Ofrag + (size_t)lane * 8;
    const unsigned short* wb = wpfrag + (size_t)lane * 8;

    #pragma unroll
    for (int kc = 0; kc < 16; ++kc) {
        short8 bf[2][2];
        #pragma unroll
        for (int nt = 0; nt < 2; ++nt) {
            size_t fb_ = ((size_t)((nt0 + nt) * 16 + kc) * 2) * 512;
            bf[nt][0] = bcs8(*(const uint4*)(wb + fb_));
            bf[nt][1] = bcs8(*(const uint4*)(wb + fb_ + 512));
        }
        #pragma unroll
        for (int mt = 0; mt < 2; ++mt) {
            size_t fa_ = ((size_t)((mt0 + mt) * 16 + kc) * 2) * 512;
            short8 ah = bcs8(*(const uint4*)(ab + fa_));
            short8 al = bcs8(*(const uint4*)(ab + fa_ + 512));
            #pragma unroll
            for (int nt = 0; nt < 2; ++nt) {
                acc[mt][nt] = mfma16(ah, bf[nt][0], acc[mt][nt]);
                acc[mt][nt] = mfma16(ah, bf[nt][1], acc[mt][nt]);
                acc[mt][nt] = mfma16(al, bf[nt][0], acc[mt][nt]);
            }
        }
    }
    #pragma unroll
    for (int mt = 0; mt < 2; ++mt)
        #pragma unroll
        for (int nt = 0; nt < 2; ++nt) {
            int c = col0 + wn * 32 + nt * 16 + l15;
            float bv = bias[c];
            #pragma unroll
            for (int r = 0; r < 4; ++r) {
                int tok = row0 + wm * 32 + mt * 16 + l4 * 4 + r;
                out[(size_t)tok * 512 + c] = acc[mt][nt][r] + bv;
            }
        }
}

// ---------------------------------------------------------------------------
extern "C" void kernel_launch(void* const* d_in, const int* in_sizes, int n_in,
                              void* d_out, int out_size, void* d_ws, size_t ws_size,
                              hipStream_t stream)
{
    const float* x      = (const float*)d_in[0];
    const float* qkv_w  = (const float*)d_in[1];
    const float* proj_w = (const float*)d_in[2];
    const float* proj_b = (const float*)d_in[3];
    float* out = (float*)d_out;

    char* ws = (char*)d_ws;
    unsigned short* xfrag  = (unsigned short*)ws;                     //  8 MiB
    unsigned short* wqfrag = (unsigned short*)(ws + 8388608);         //  3 MiB
    unsigned short* wpfrag = (unsigned short*)(ws + 11534336);        //  1 MiB
    unsigned short* qd     = (unsigned short*)(ws + 12582912);        //  4 MiB
    unsigned short* kfrag  = (unsigned short*)(ws + 16777216);        //  4 MiB
    unsigned short* vfrag  = (unsigned short*)(ws + 20971520);        //  4 MiB
    unsigned short* Ofrag  = (unsigned short*)(ws + 25165824);        //  8 MiB (end 32 MiB)

    prep<<<512, 256, 0, stream>>>(qkv_w, proj_w, x, wqfrag, wpfrag, xfrag);
    gemm_qkv<<<dim3(12, 64), 256, 0, stream>>>(xfrag, wqfrag, qd, kfrag, vfrag);
    attn<<<512, 256, 0, stream>>>(qd, kfrag, vfrag, Ofrag);
    gemm_proj<<<dim3(8, 64), 256, 0, stream>>>(Ofrag, wpfrag, proj_b, out);
}